// Round 1
// baseline (144.476 us; speedup 1.0000x reference)
//
#include <hip/hip_runtime.h>

namespace {
constexpr int N_ = 8, C_ = 32, H_ = 256, W_ = 512, DISP_ = 25;
constexpr int CH_STRIDE = H_ * W_;  // 131072 elements between channels
}

// One thread owns 4 consecutive output columns (w0..w0+3) for one (n,h) row,
// and accumulates all 25 disparities in registers. 128 threads cover a row
// (W=512); a 256-thread block covers 2 rows. Memory-bound design:
// x read once, y read via 7 overlapping float4 windows (L1-served overlap).
__global__ __launch_bounds__(256) void rescost_kernel(
    const float* __restrict__ x, const float* __restrict__ y,
    float* __restrict__ out) {
  const int lane = threadIdx.x;
  const int t = lane & 127;                        // thread-in-row
  const int r = (blockIdx.x << 1) | (lane >> 7);   // global row in [0, N*H)
  const int n = r >> 8;                            // H = 256
  const int h = r & (H_ - 1);
  const int w0 = t << 2;

  // Clamped, 16B-aligned y-window offsets covering columns [w0-12, w0+16).
  // Each 4-wide window is either fully in-range or fully out-of-range
  // (w0-12 is a multiple of 4); clamped (garbage) windows only ever feed
  // (w,i) pairs that the epilogue zeroes.
  int yoff[7];
#pragma unroll
  for (int k = 0; k < 7; ++k) {
    int idx = w0 - 12 + 4 * k;
    idx = idx < 0 ? 0 : idx;
    idx = idx > (W_ - 4) ? (W_ - 4) : idx;
    yoff[k] = idx;
  }

  const size_t row_base = ((size_t)n * C_ * H_ + (size_t)h) * W_;
  const float* xp = x + row_base + w0;
  const float* yp = y + row_base;

  float acc[DISP_][4];
#pragma unroll
  for (int i = 0; i < DISP_; ++i)
#pragma unroll
    for (int cw = 0; cw < 4; ++cw) acc[i][cw] = 0.0f;

  for (int c = 0; c < C_; ++c) {
    const float4 xv = *reinterpret_cast<const float4*>(xp);
    float4 yv[7];
#pragma unroll
    for (int k = 0; k < 7; ++k)
      yv[k] = *reinterpret_cast<const float4*>(yp + yoff[k]);

    // Flatten window to scalar regs (all constant indices -> SROA to VGPRs).
    float ywin[28];
#pragma unroll
    for (int k = 0; k < 7; ++k) {
      ywin[4 * k + 0] = yv[k].x;
      ywin[4 * k + 1] = yv[k].y;
      ywin[4 * k + 2] = yv[k].z;
      ywin[4 * k + 3] = yv[k].w;
    }
    const float xs0 = xv.x, xs1 = xv.y, xs2 = xv.z, xs3 = xv.w;

#pragma unroll
    for (int i = 0; i < DISP_; ++i) {
      // out[w0+cw][i] needs y[w0+cw-i+12] = ywin[cw + 24 - i]
      acc[i][0] += fabsf(xs0 - ywin[0 + 24 - i]);
      acc[i][1] += fabsf(xs1 - ywin[1 + 24 - i]);
      acc[i][2] += fabsf(xs2 - ywin[2 + 24 - i]);
      acc[i][3] += fabsf(xs3 - ywin[3 + 24 - i]);
    }

    xp += CH_STRIDE;
    yp += CH_STRIDE;
  }

  // Epilogue: zero out-of-overlap (w,i) pairs, store coalesced float4.
  // out index: ((n*DISP + i)*H + h)*W + w
  float* op = out + ((size_t)n * DISP_ * H_ + (size_t)h) * W_ + w0;
#pragma unroll
  for (int i = 0; i < DISP_; ++i) {
    const int j0 = w0 - i + 12;  // y column used by cw=0
    float4 v;
    v.x = ((unsigned)(j0 + 0) < (unsigned)W_) ? acc[i][0] : 0.0f;
    v.y = ((unsigned)(j0 + 1) < (unsigned)W_) ? acc[i][1] : 0.0f;
    v.z = ((unsigned)(j0 + 2) < (unsigned)W_) ? acc[i][2] : 0.0f;
    v.w = ((unsigned)(j0 + 3) < (unsigned)W_) ? acc[i][3] : 0.0f;
    *reinterpret_cast<float4*>(op + (size_t)i * CH_STRIDE) = v;
  }
}

extern "C" void kernel_launch(void* const* d_in, const int* in_sizes, int n_in,
                              void* d_out, int out_size, void* d_ws, size_t ws_size,
                              hipStream_t stream) {
  const float* x = (const float*)d_in[0];
  const float* y = (const float*)d_in[1];
  float* out = (float*)d_out;
  dim3 grid(N_ * H_ / 2);   // 2 rows per 256-thread block
  dim3 block(256);
  hipLaunchKernelGGL(rescost_kernel, grid, block, 0, stream, x, y, out);
}

// Round 2
// 135.660 us; speedup vs baseline: 1.0650x; 1.0650x over previous
//
#include <hip/hip_runtime.h>

namespace {
constexpr int N_ = 8, C_ = 32, H_ = 256, W_ = 512, DISP_ = 25;
constexpr int CH_STRIDE = H_ * W_;  // 131072 elements between channels
}

// One thread owns 4 consecutive output columns for one (n,h) row and
// accumulates all 25 disparities in registers (AccVGPRs). 128 threads = one
// full row; 2048 blocks. Explicit double-buffered prefetch of the next
// channel's x/y windows hides L2/L3/HBM latency under the 200-VALU compute
// phase (we are register-occupancy-limited at 2 waves/SIMD, so ILP is free).
__global__ __launch_bounds__(128, 2) void rescost_kernel(
    const float* __restrict__ x, const float* __restrict__ y,
    float* __restrict__ out) {
  const int t = threadIdx.x;                 // 0..127
  const int r = blockIdx.x;                  // row in [0, N*H)
  const int n = r >> 8;                      // H = 256
  const int h = r & (H_ - 1);
  const int w0 = t << 2;

  // Clamped, 16B-aligned y-window offsets covering columns [w0-12, w0+16).
  // Each 4-wide window is either fully in-range or fully OOB (w0-12 is a
  // multiple of 4); clamped (garbage) windows only feed epilogue-zeroed pairs.
  int yoff[7];
#pragma unroll
  for (int k = 0; k < 7; ++k) {
    int idx = w0 - 12 + 4 * k;
    idx = idx < 0 ? 0 : idx;
    idx = idx > (W_ - 4) ? (W_ - 4) : idx;
    yoff[k] = idx;
  }

  const size_t row_base = ((size_t)n * C_ * H_ + (size_t)h) * W_;
  const float* xp = x + row_base + w0;
  const float* yp = y + row_base;

  float acc[DISP_][4];
#pragma unroll
  for (int i = 0; i < DISP_; ++i)
#pragma unroll
    for (int cw = 0; cw < 4; ++cw) acc[i][cw] = 0.0f;

  float4 xv0, xv1;
  float4 yv0[7], yv1[7];

#define LOADP(XV, YV, c)                                                   \
  do {                                                                     \
    const float* xq = xp + (size_t)(c)*CH_STRIDE;                          \
    const float* yq = yp + (size_t)(c)*CH_STRIDE;                          \
    XV = *reinterpret_cast<const float4*>(xq);                             \
    _Pragma("unroll") for (int k = 0; k < 7; ++k) YV[k] =                  \
        *reinterpret_cast<const float4*>(yq + yoff[k]);                    \
  } while (0)

#define COMPUTE(XV, YV)                                                    \
  do {                                                                     \
    float ywin[28];                                                        \
    _Pragma("unroll") for (int k = 0; k < 7; ++k) {                        \
      ywin[4 * k + 0] = YV[k].x;                                           \
      ywin[4 * k + 1] = YV[k].y;                                           \
      ywin[4 * k + 2] = YV[k].z;                                           \
      ywin[4 * k + 3] = YV[k].w;                                           \
    }                                                                      \
    const float xs0 = XV.x, xs1 = XV.y, xs2 = XV.z, xs3 = XV.w;            \
    _Pragma("unroll") for (int i = 0; i < DISP_; ++i) {                    \
      acc[i][0] += fabsf(xs0 - ywin[0 + 24 - i]);                          \
      acc[i][1] += fabsf(xs1 - ywin[1 + 24 - i]);                          \
      acc[i][2] += fabsf(xs2 - ywin[2 + 24 - i]);                          \
      acc[i][3] += fabsf(xs3 - ywin[3 + 24 - i]);                          \
    }                                                                      \
  } while (0)

  // Software pipeline, unrolled by 2 with named buffers (no dynamic indexing).
  LOADP(xv0, yv0, 0);
#pragma unroll 1
  for (int c = 0; c < C_ - 2; c += 2) {
    LOADP(xv1, yv1, c + 1);
    COMPUTE(xv0, yv0);
    LOADP(xv0, yv0, c + 2);
    COMPUTE(xv1, yv1);
  }
  LOADP(xv1, yv1, C_ - 1);
  COMPUTE(xv0, yv0);  // c = 30
  COMPUTE(xv1, yv1);  // c = 31

#undef LOADP
#undef COMPUTE

  // Epilogue: zero out-of-overlap (w,i) pairs, store coalesced float4.
  float* op = out + ((size_t)n * DISP_ * H_ + (size_t)h) * W_ + w0;
#pragma unroll
  for (int i = 0; i < DISP_; ++i) {
    const int j0 = w0 - i + 12;  // y column used by cw=0
    float4 v;
    v.x = ((unsigned)(j0 + 0) < (unsigned)W_) ? acc[i][0] : 0.0f;
    v.y = ((unsigned)(j0 + 1) < (unsigned)W_) ? acc[i][1] : 0.0f;
    v.z = ((unsigned)(j0 + 2) < (unsigned)W_) ? acc[i][2] : 0.0f;
    v.w = ((unsigned)(j0 + 3) < (unsigned)W_) ? acc[i][3] : 0.0f;
    *reinterpret_cast<float4*>(op + (size_t)i * CH_STRIDE) = v;
  }
}

extern "C" void kernel_launch(void* const* d_in, const int* in_sizes, int n_in,
                              void* d_out, int out_size, void* d_ws, size_t ws_size,
                              hipStream_t stream) {
  const float* x = (const float*)d_in[0];
  const float* y = (const float*)d_in[1];
  float* out = (float*)d_out;
  dim3 grid(N_ * H_);  // one (n,h) row per 128-thread block
  dim3 block(128);
  hipLaunchKernelGGL(rescost_kernel, grid, block, 0, stream, x, y, out);
}